// Round 11
// baseline (78.767 us; speedup 1.0000x reference)
//
#include <hip/hip_runtime.h>

#define NQ 14
#define NSTATE (1 << NQ)
#define NT 256
#define AMPS 64

typedef float  f2  __attribute__((ext_vector_type(2)));
typedef __fp16 h2v __attribute__((ext_vector_type(2)));

// LDS: gate region st[0,16384) h2 (psi-address space, b128-friendly swizzle);
// E region rows stride 68 h2: [0, 256*68=17408) h2 — aliased in time (barriers).
#define N_H2 17408
#define OFF_BTAB  (N_H2*4)                 // 69632
#define OFF_RX3   (OFF_BTAB + 28*8)
#define OFF_XX2   (OFF_RX3 + 28*4)
#define OFF_RED   (OFF_XX2 + 14*4)
#define SMEM_BYTES (OFF_RED + 4*NQ*4)      // ~70.2 KB -> 2 blocks/CU

__device__ __forceinline__ f2 cmul(f2 a, f2 b){
    f2 r;
    r.x = fmaf(a.x, b.x, -a.y * b.y);
    r.y = fmaf(a.x, b.y,  a.y * b.x);
    return r;
}
// A' = c*A + s*(B.y,-B.x);  B' = c*B + s*(A.y,-A.x)   (plain f32; compiler schedules)
__device__ __forceinline__ void rot2(f2& A, f2& B, float c, float s){
    f2 a = A, b = B;
    A.x = fmaf(c, a.x,  s * b.y);
    A.y = fmaf(c, a.y, -s * b.x);
    B.x = fmaf(c, b.x,  s * a.y);
    B.y = fmaf(c, b.y, -s * a.x);
}
__device__ __forceinline__ h2v pack(f2 v){ return __builtin_amdgcn_cvt_pkrtz(v.x, v.y); }
__device__ __forceinline__ f2  unpack(h2v h){ return (f2){(float)h.x, (float)h.y}; }
__device__ __forceinline__ f2  unpack_u(unsigned w){ h2v h = __builtin_bit_cast(h2v, w); return unpack(h); }

template<int CTRL>
__device__ __forceinline__ f2 qperm(f2 v){
    int x = __builtin_amdgcn_mov_dpp(__float_as_int(v.x), CTRL, 0xf, 0xf, true);
    int y = __builtin_amdgcn_mov_dpp(__float_as_int(v.y), CTRL, 0xf, 0xf, true);
    return (f2){__int_as_float(x), __int_as_float(y)};
}
template<int CTRL>
__device__ __forceinline__ float fdpp(float v){
    return __int_as_float(__builtin_amdgcn_mov_dpp(__float_as_int(v), CTRL, 0xf, 0xf, true));
}
// cross-lane rotation update: X' = c*X + s*(P.y, -P.x)
__device__ __forceinline__ f2 rotl(f2 X, f2 P, float c, float s){
    f2 r;
    r.x = fmaf(c, X.x,  s * P.y);
    r.y = fmaf(c, X.y, -s * P.x);
    return r;
}

template<int P, int M>
__device__ __forceinline__ void applyXX(f2* amp, float c, float s){
    #pragma unroll
    for (int L = 0; L < AMPS; ++L)
        if (!((L >> P) & 1)) rot2(amp[L], amp[L ^ M], c, s);
}
template<int R>
__device__ __forceinline__ void applyRX(f2* amp, float c, float s){
    #pragma unroll
    for (int L = 0; L < AMPS; ++L)
        if (!((L >> R) & 1)) rot2(amp[L], amp[L | (1 << R)], c, s);
}

// ---- pre-kernel: f = pi^-1(j) (ascending chain; direction verified R6-R10).
// P2 enumeration: j = ((L'>>1)&31) | (t2<<5) | ((L'&1)<<13).
// Store tbl[t2*64 + L'] = f + 4*(f>>6)  (E-layout slot premultiplied; max 17403 < 65536).
__global__ void perm_tbl_kernel(unsigned short* __restrict__ tbl)
{
    const int j = blockIdx.x * blockDim.x + threadIdx.x;   // 0..16383
    int x = j;
    #pragma unroll
    for (int w = 0; w < NQ; ++w) {
        const int p1 = 13 - w;
        const int p2 = 13 - ((w + 1) % NQ);
        const int pt = 13 - ((w + 2) % NQ);
        const int cond = ((x >> p1) & ~(x >> p2)) & 1;
        x ^= cond << pt;
    }
    const int t2 = (j >> 5) & 0xFF;
    const int Lp = ((j >> 13) & 1) | ((j & 31) << 1);
    tbl[t2 * 64 + Lp] = (unsigned short)(x + 4 * (x >> 6));
}

// State bit j -> ownership:
// P1: local L[5:0]=j[12:7]; lanes l0=j6,l1=j5,l2=j4,l3=j3,l4=j2,l5=j1; wave: t6=j0,t7=j13.
// P2: local L'0=j13,L'1=j0,L'2=j1,L'3=j2,L'4=j3,L'5=j4; lanes t2b0=j5..t2b5=j10; wave t2b6=j11,t2b7=j12.
// psi-addr (h2) = t1*64 + (L ^ W1(t1)), W1 = (b0<<2)|(b1<<3)|((b0^b1^b2)<<4), b=t1 bits.
__global__ void __launch_bounds__(NT, 2)
qsim_kernel(const float* __restrict__ cp, const float* __restrict__ p,
            const unsigned short* __restrict__ tblD, float* __restrict__ out)
{
    extern __shared__ __align__(16) char smem[];
    h2v*   st   = reinterpret_cast<h2v*>(smem);
    uint4* stq  = reinterpret_cast<uint4*>(smem);
    f2*    Btab = reinterpret_cast<f2*>(smem + OFF_BTAB);
    float* rx3c = reinterpret_cast<float*>(smem + OFF_RX3);
    float* rx3s = rx3c + 14;
    float* xx2c = reinterpret_cast<float*>(smem + OFF_XX2);
    float* xx2s = xx2c + 7;
    float* red  = reinterpret_cast<float*>(smem + OFF_RED);

    const int b = blockIdx.x;
    const int t = threadIdx.x;
    const float* pb  = p  + b * 42;
    const float* cpb = cp + b * 14;

    // ---- per-block tables (RX1 x XX1 x RZ fused into 7 two-qubit groups) ----
    if (t < 7) {
        const int ws = t, wa = 2*ws, wb = 2*ws + 1;
        float sa, ca; sincosf(0.5f * pb[wa], &sa, &ca);
        float sb, cb; sincosf(0.5f * pb[wb], &sb, &cb);
        f2 s00 = {ca*cb, 0.f};
        f2 s01 = {0.f, -ca*sb};
        f2 s10 = {0.f, -sa*cb};
        f2 s11 = {-sa*sb, 0.f};
        float sx, cx; sincosf(0.5f * cpb[ws], &sx, &cx);
        rot2(s00, s11, cx, sx);
        rot2(s01, s10, cx, sx);
        const float ga = 0.5f * pb[14 + wa], gb = 0.5f * pb[14 + wb];
        float sA, cA; sincosf(ga + gb, &sA, &cA);
        float sB, cB; sincosf(gb - ga, &sB, &cB);
        s00 = cmul(s00, (f2){cA, -sA});
        s11 = cmul(s11, (f2){cA,  sA});
        s01 = cmul(s01, (f2){cB,  sB});
        s10 = cmul(s10, (f2){cB, -sB});
        const int g = 6 - ws;   // group g covers state bits (2g+1, 2g); idx = bit(2g+1)*2 + bit(2g)
        Btab[g*4+0] = s00; Btab[g*4+1] = s01; Btab[g*4+2] = s10; Btab[g*4+3] = s11;
    } else if (t >= 64 && t < 78) {
        const int w = t - 64;
        float s, c; sincosf(0.5f * pb[28 + w], &s, &c);
        rx3c[w] = c; rx3s[w] = s;
    } else if (t >= 128 && t < 135) {
        const int g = t - 128;
        float s, c; sincosf(0.5f * cpb[7 + g], &s, &c);
        xx2c[g] = c; xx2s[g] = s;
    }
    __syncthreads();

    f2 amp[AMPS];
    float gc, gs;
    #define LOADXX(g) do { gc = xx2c[g]; gs = xx2s[g]; } while (0)
    #define LOADRX(w) do { gc = rx3c[w]; gs = rx3s[w]; } while (0)

    // ==== P1: build + XX(1,2),(3,4),(5,6) local + XX(7,8) quad + RX(1..8) ====
    {
        // crumb indices from (t, L):  j0=t6 j1=t5 j2=t4 j3=t3 j4=t2 j5=t1 j6=t0 j13=t7
        const int i0 = (((t >> 5) & 1) << 1) | ((t >> 6) & 1);
        const int i1 = (((t >> 3) & 1) << 1) | ((t >> 4) & 1);
        const int i2 = (((t >> 1) & 1) << 1) | ((t >> 2) & 1);
        f2 U = cmul(cmul(Btab[i0], Btab[4 + i1]), Btab[8 + i2]);
        f2 B3v0 = Btab[12 + (t & 1)];                 // L0=0: idx3 = t0
        f2 B3v1 = Btab[12 + 2 + (t & 1)];             // L0=1
        f2 B6v0 = Btab[24 + (((t >> 7) & 1) << 1)];   // L5=0: idx6 = t7*2
        f2 B6v1 = Btab[24 + (((t >> 7) & 1) << 1) + 1];
        f2 UB0 = cmul(U, B3v0), UB1 = cmul(U, B3v1);
        f2 W00 = cmul(UB0, B6v0), W01 = cmul(UB1, B6v0);
        f2 W10 = cmul(UB0, B6v1), W11 = cmul(UB1, B6v1);
        #pragma unroll
        for (int m = 0; m < 16; ++m) {                // m = L[4:1]
            f2 H = cmul(Btab[20 + (m >> 2)], Btab[16 + (m & 3)]);  // B5[idx5]*B4[idx4]
            amp[(m << 1)]          = cmul(W00, H);
            amp[(m << 1) | 1]      = cmul(W01, H);
            amp[32 | (m << 1)]     = cmul(W10, H);
            amp[32 | (m << 1) | 1] = cmul(W11, H);
        }
        LOADXX(0); applyXX<5, 0x30>(amp, gc, gs);     // XX(1,2) bits(12,11)=(L5,L4)
        LOADXX(1); applyXX<3, 0x0C>(amp, gc, gs);     // XX(3,4) bits(10,9)=(L3,L2)
        LOADXX(2); applyXX<1, 0x03>(amp, gc, gs);     // XX(5,6) bits(8,7)=(L1,L0)
        LOADXX(3);                                    // XX(7,8) bits(6,5)=(l0,l1): lane^3
        #pragma unroll
        for (int L = 0; L < AMPS; ++L) { f2 pv = qperm<0x1B>(amp[L]); amp[L] = rotl(amp[L], pv, gc, gs); }
        LOADRX(1); applyRX<5>(amp, gc, gs);
        LOADRX(2); applyRX<4>(amp, gc, gs);
        LOADRX(3); applyRX<3>(amp, gc, gs);
        LOADRX(4); applyRX<2>(amp, gc, gs);
        LOADRX(5); applyRX<1>(amp, gc, gs);
        LOADRX(6); applyRX<0>(amp, gc, gs);
        LOADRX(7);                                    // bit6 = l0: lane^1
        #pragma unroll
        for (int L = 0; L < AMPS; ++L) { f2 pv = qperm<0xB1>(amp[L]); amp[L] = rotl(amp[L], pv, gc, gs); }
        LOADRX(8);                                    // bit5 = l1: lane^2
        #pragma unroll
        for (int L = 0; L < AMPS; ++L) { f2 pv = qperm<0x4E>(amp[L]); amp[L] = rotl(amp[L], pv, gc, gs); }
        // write: 16 x ds_write_b128 at uint4 index t*16 + (m ^ (W1>>2))
        const int w1h = ((t & 1) | ((t >> 1) & 1) << 1 | (((t ^ (t >> 1) ^ (t >> 2)) & 1) << 2));
        #pragma unroll
        for (int m = 0; m < 16; ++m) {
            uint4 pk;
            pk.x = __builtin_bit_cast(unsigned, pack(amp[4*m]));
            pk.y = __builtin_bit_cast(unsigned, pack(amp[4*m + 1]));
            pk.z = __builtin_bit_cast(unsigned, pack(amp[4*m + 2]));
            pk.w = __builtin_bit_cast(unsigned, pack(amp[4*m + 3]));
            stq[t * 16 + (m ^ w1h)] = pk;
        }
    }
    __syncthreads();

    // ==== P2: strided read + XX(9,10),(11,12),(13,0) + RX(9..13,0) all local ====
    {
        uint4 tv[8];
        {
            const uint4* tq = reinterpret_cast<const uint4*>(tblD) + t * 8;
            #pragma unroll
            for (int g = 0; g < 8; ++g) tv[g] = tq[g];   // issue early
        }
        const int sw2 = ((t & 2) >> 1) | ((t & 1) << 1); // t1 low2 = (j6,j5) = (t2b1,t2b0)
        const int Lf  = t >> 2;                           // P1-local L of my amps (thread-const)
        const int w1b = ((sw2 & 1) << 2) | (((sw2 >> 1) & 1) << 3) | ((((sw2 ^ (sw2 >> 1)) & 1)) << 4);
        #pragma unroll
        for (int Lp = 0; Lp < AMPS; ++Lp) {
            const int rev = ((Lp >> 5) & 1) | (((Lp >> 4) & 1) << 1) | (((Lp >> 3) & 1) << 2)
                          | (((Lp >> 2) & 1) << 3) | (((Lp >> 1) & 1) << 4) | ((Lp & 1) << 5);
            const int t1  = sw2 | (rev << 2);
            const int w1v = w1b ^ ((rev & 1) << 4);       // b2 = t1 bit2 = rev bit0
            amp[Lp] = unpack(st[t1 * 64 + (Lf ^ w1v)]);
        }
        LOADXX(4); applyXX<5, 0x30>(amp, gc, gs);     // XX(9,10)  bits(4,3)=(L'5,L'4)
        LOADXX(5); applyXX<3, 0x0C>(amp, gc, gs);     // XX(11,12) bits(2,1)=(L'3,L'2)
        LOADXX(6); applyXX<1, 0x03>(amp, gc, gs);     // XX(13,0)  bits(0,13)=(L'1,L'0)
        LOADRX(9);  applyRX<5>(amp, gc, gs);
        LOADRX(10); applyRX<4>(amp, gc, gs);
        LOADRX(11); applyRX<3>(amp, gc, gs);
        LOADRX(12); applyRX<2>(amp, gc, gs);
        LOADRX(13); applyRX<1>(amp, gc, gs);
        LOADRX(0);  applyRX<0>(amp, gc, gs);
        __syncthreads();   // all gate-layout reads done; E layout may overwrite
        // scatter: table already holds eslot = f + 4*(f>>6)  (rows of 64, stride 68)
        #pragma unroll
        for (int Lp = 0; Lp < AMPS; ++Lp) {
            const unsigned word = (Lp & 4) ? ((Lp & 2) ? tv[Lp >> 3].w : tv[Lp >> 3].z)
                                           : ((Lp & 2) ? tv[Lp >> 3].y : tv[Lp >> 3].x);
            const unsigned fp = (Lp & 1) ? (word >> 16) : (word & 0xffffu);
            st[fp] = pack(amp[Lp]);
        }
    }
    __syncthreads();

    // ==== E: 16 x ds_read_b128; f = t*64 + k ====
    //   k[5:0] -> wires 13..8 (tree U0..U5); lane[5:0] -> wires 7..2 (butterfly);
    //   wave[1:0] -> wires 1,0.
    {
        float T = 0.f, U0 = 0.f, U1 = 0.f, U2 = 0.f, U3 = 0.f, U4 = 0.f, U5 = 0.f;
        #pragma unroll
        for (int m = 0; m < 16; ++m) {
            const uint4 v = stq[t * 17 + m];
            const f2 a0 = unpack_u(v.x), a1 = unpack_u(v.y), a2 = unpack_u(v.z), a3 = unpack_u(v.w);
            const float q0 = fmaf(a0.x, a0.x, a0.y * a0.y);
            const float q1 = fmaf(a1.x, a1.x, a1.y * a1.y);
            const float q2 = fmaf(a2.x, a2.x, a2.y * a2.y);
            const float q3 = fmaf(a3.x, a3.x, a3.y * a3.y);
            const float t23 = q2 + q3;
            const float Tc = (q0 + q1) + t23;
            U0 += q1 + q3;                 // k bit0
            U1 += t23;                     // k bit1
            if (m & 1) U2 += Tc;           // k bit2
            if (m & 2) U3 += Tc;
            if (m & 4) U4 += Tc;
            if (m & 8) U5 += Tc;
            T += Tc;
        }
        // sign-tracking butterfly over 6 lane bits (valid at lane 0); masks 1,2 via DPP
        float s = T;
        float d0, d1, d2, d3, d4, d5;
        {
            float o;
            o = fdpp<0xB1>(s);      d0 = s - o; s += o;
            o = fdpp<0x4E>(d0);     d0 += o;
            o = fdpp<0x4E>(s);      d1 = s - o; s += o;
            o = __shfl_xor(d0, 4);  d0 += o;
            o = __shfl_xor(d1, 4);  d1 += o;
            o = __shfl_xor(s, 4);   d2 = s - o; s += o;
            o = __shfl_xor(d0, 8);  d0 += o;
            o = __shfl_xor(d1, 8);  d1 += o;
            o = __shfl_xor(d2, 8);  d2 += o;
            o = __shfl_xor(s, 8);   d3 = s - o; s += o;
            o = __shfl_xor(d0, 16); d0 += o;
            o = __shfl_xor(d1, 16); d1 += o;
            o = __shfl_xor(d2, 16); d2 += o;
            o = __shfl_xor(d3, 16); d3 += o;
            o = __shfl_xor(s, 16);  d4 = s - o; s += o;
            o = __shfl_xor(d0, 32); d0 += o;
            o = __shfl_xor(d1, 32); d1 += o;
            o = __shfl_xor(d2, 32); d2 += o;
            o = __shfl_xor(d3, 32); d3 += o;
            o = __shfl_xor(d4, 32); d4 += o;
            o = __shfl_xor(s, 32);  d5 = s - o; s += o;
        }
        float V0 = U0, V1 = U1, V2 = U2, V3 = U3, V4 = U4, V5 = U5;
        V0 += fdpp<0xB1>(V0); V1 += fdpp<0xB1>(V1); V2 += fdpp<0xB1>(V2);
        V3 += fdpp<0xB1>(V3); V4 += fdpp<0xB1>(V4); V5 += fdpp<0xB1>(V5);
        V0 += fdpp<0x4E>(V0); V1 += fdpp<0x4E>(V1); V2 += fdpp<0x4E>(V2);
        V3 += fdpp<0x4E>(V3); V4 += fdpp<0x4E>(V4); V5 += fdpp<0x4E>(V5);
        #pragma unroll
        for (int m = 4; m < 64; m <<= 1) {
            V0 += __shfl_xor(V0, m);
            V1 += __shfl_xor(V1, m);
            V2 += __shfl_xor(V2, m);
            V3 += __shfl_xor(V3, m);
            V4 += __shfl_xor(V4, m);
            V5 += __shfl_xor(V5, m);
        }
        if ((t & 63) == 0) {
            const int wv = t >> 6;           // wave bits = f bits 12,13
            float* r = red + wv * NQ;
            r[0]  = (wv & 2) ? -s : s;       // f13 -> wire 0
            r[1]  = (wv & 1) ? -s : s;       // f12 -> wire 1
            r[2]  = d5;                      // f11 -> wire 2
            r[3]  = d4;
            r[4]  = d3;
            r[5]  = d2;
            r[6]  = d1;
            r[7]  = d0;                      // f6 -> wire 7
            r[8]  = s - 2.f * V5;            // f5 -> wire 8
            r[9]  = s - 2.f * V4;
            r[10] = s - 2.f * V3;
            r[11] = s - 2.f * V2;
            r[12] = s - 2.f * V1;
            r[13] = s - 2.f * V0;            // f0 -> wire 13
        }
    }
    __syncthreads();
    if (t < NQ) {
        out[b * NQ + t] = (red[t] + red[NQ + t]) + (red[2 * NQ + t] + red[3 * NQ + t]);
    }
    #undef LOADXX
    #undef LOADRX
}

extern "C" void kernel_launch(void* const* d_in, const int* in_sizes, int n_in,
                              void* d_out, int out_size, void* d_ws, size_t ws_size,
                              hipStream_t stream)
{
    (void)n_in; (void)out_size; (void)ws_size;
    const float* cp = (const float*)d_in[0];
    const float* p  = (const float*)d_in[1];
    float* out = (float*)d_out;
    unsigned short* tbl = (unsigned short*)d_ws;        // 32 KiB
    const int B = in_sizes[0] / NQ;   // 512

    perm_tbl_kernel<<<NSTATE / 256, 256, 0, stream>>>(tbl);

    (void)hipFuncSetAttribute(reinterpret_cast<const void*>(qsim_kernel),
                              hipFuncAttributeMaxDynamicSharedMemorySize, SMEM_BYTES);
    qsim_kernel<<<B, NT, SMEM_BYTES, stream>>>(cp, p, tbl, out);
}